// Round 2
// 950.396 us; speedup vs baseline: 1.0335x; 1.0335x over previous
//
#include <hip/hip_runtime.h>
#include <hip/hip_bf16.h>
#include <math.h>

typedef __hip_bfloat16 bf16;
typedef __attribute__((ext_vector_type(8))) short short8;
typedef __attribute__((ext_vector_type(4))) float floatx4;

constexpr int Bc = 4, Sc = 1024, Dc = 2048, Hc = 16, HDc = 128, Ic = 8192;
constexpr int QKVLD = 3 * Dc;  // 6144

__device__ __forceinline__ float bf2f(bf16 x){ return __bfloat162float(x); }
__device__ __forceinline__ bf16 f2bf(float x){ return __float2bfloat16(x); }

__device__ __forceinline__ uint4 pack8(float4 a, float4 b){
    union { uint4 u; bf16 h[8]; } r;
    r.h[0]=f2bf(a.x); r.h[1]=f2bf(a.y); r.h[2]=f2bf(a.z); r.h[3]=f2bf(a.w);
    r.h[4]=f2bf(b.x); r.h[5]=f2bf(b.y); r.h[6]=f2bf(b.z); r.h[7]=f2bf(b.w);
    return r.u;
}

// async global->LDS, 16B/lane; lds must be the WAVE-UNIFORM base (deposit = base + lane*16)
__device__ __forceinline__ void glds16(void* lds, const void* g){
    __builtin_amdgcn_global_load_lds(
        (__attribute__((address_space(1))) void*)(size_t)g,
        (__attribute__((address_space(3))) void*)lds,
        16, 0, 0);
}

// ---- weight convert fp32 -> bf16, 8 el/thread -----------------------------------------
__global__ __launch_bounds__(256)
void conv_w(const float* __restrict__ src, bf16* __restrict__ dst){
    const size_t i = ((size_t)blockIdx.x * 256 + threadIdx.x) * 8;
    float4 a = *(const float4*)(src + i);
    float4 b = *(const float4*)(src + i + 4);
    *(uint4*)(dst + i) = pack8(a, b);
}

// ---- 4 D*D weights in one launch (2048 blocks each) -----------------------------------
__global__ __launch_bounds__(256)
void conv_w4(const float* __restrict__ s0, const float* __restrict__ s1,
             const float* __restrict__ s2, const float* __restrict__ s3,
             bf16* __restrict__ dst){
    const int id = blockIdx.x >> 11;
    const float* src = (id == 0) ? s0 : (id == 1) ? s1 : (id == 2) ? s2 : s3;
    const size_t i = ((size_t)(blockIdx.x & 2047) * 256 + threadIdx.x) * 8;
    float4 a = *(const float4*)(src + i);
    float4 b = *(const float4*)(src + i + 4);
    *(uint4*)(dst + (size_t)id * Dc * Dc + i) = pack8(a, b);
}

// ---- dst[i] = bias[i % D] + src[i]  (fp32, 8 el/thread) -------------------------------
__global__ __launch_bounds__(256)
void init_add(float* __restrict__ dst, const float* __restrict__ bias,
              const float* __restrict__ src){
    const size_t i = ((size_t)blockIdx.x * 256 + threadIdx.x) * 8;
    const int col = (int)(i & (Dc - 1));
    float4 a = *(const float4*)(src + i);
    float4 b = *(const float4*)(src + i + 4);
    float4 ba = *(const float4*)(bias + col);
    float4 bb = *(const float4*)(bias + col + 4);
    a.x += ba.x; a.y += ba.y; a.z += ba.z; a.w += ba.w;
    b.x += bb.x; b.y += bb.y; b.z += bb.z; b.w += bb.w;
    *(float4*)(dst + i) = a;
    *(float4*)(dst + i + 4) = b;
}

// ---- LayerNorm: one block per row, D=2048, 256 thr x 8 el; INF32: input dtype ---------
template<int INF32>
__global__ __launch_bounds__(256)
void ln_kernel(const void* __restrict__ x, const float* __restrict__ w,
               const float* __restrict__ b, bf16* __restrict__ y)
{
    const int row = blockIdx.x;
    const int t = threadIdx.x;
    float f[8], s = 0.f, s2 = 0.f;
    if (INF32) {
        const float* xr = (const float*)x + (size_t)row * Dc + t * 8;
        float4 a = *(const float4*)xr, c = *(const float4*)(xr + 4);
        f[0]=a.x; f[1]=a.y; f[2]=a.z; f[3]=a.w; f[4]=c.x; f[5]=c.y; f[6]=c.z; f[7]=c.w;
    } else {
        union { uint4 u; bf16 h[8]; } ld;
        ld.u = *(const uint4*)((const bf16*)x + (size_t)row * Dc + t * 8);
#pragma unroll
        for (int j = 0; j < 8; ++j) f[j] = bf2f(ld.h[j]);
    }
#pragma unroll
    for (int j = 0; j < 8; ++j) { s += f[j]; s2 += f[j] * f[j]; }
#pragma unroll
    for (int off = 32; off; off >>= 1) { s += __shfl_xor(s, off); s2 += __shfl_xor(s2, off); }
    __shared__ float red[8];
    const int wave = t >> 6, lane = t & 63;
    if (lane == 0) { red[wave] = s; red[4 + wave] = s2; }
    __syncthreads();
    s  = red[0] + red[1] + red[2] + red[3];
    s2 = red[4] + red[5] + red[6] + red[7];
    const float mean = s * (1.0f / Dc);
    const float var  = s2 * (1.0f / Dc) - mean * mean;
    const float rs   = rsqrtf(var + 1e-5f);
    union { uint4 u; bf16 h[8]; } st;
#pragma unroll
    for (int j = 0; j < 8; ++j) {
        const int col = t * 8 + j;
        st.h[j] = f2bf((f[j] - mean) * rs * w[col] + b[col]);
    }
    *(uint4*)&y[(size_t)row * Dc + t * 8] = st.u;
}

// =======================================================================================
// GEMM C[M,N] = epi(A[M,K] @ W[N,K]^T + bias) -- 256x256 tile, BK=64, 8 waves (2Mx4N),
// 8-phase schedule with counted vmcnt (T3+T4), setprio (T5), XCD swizzle (T1),
// rotation-swizzled LDS (conflict-free), global_load_lds width-16 staging.
// EPI: 1 *scale, 2 exact GELU, 3 +residual, 4 fused-QKV, 5 atomic fp32 (no bias)
// split-K via blockIdx.z (EPI=5 accumulates atomically into pre-initialized fp32 C).
//
// LDS map (byte offsets), buf b in {0,1}:
//   A region:  b*65536 + mh*16384 + lr*128 + g*16
//   B region:  b*65536 + 32768   + lr*128 + g*16
// granule g at row lr holds global k-chunk (g - lr) & 7 (rotation swizzle; read side
// uses granule (chunk + lr) & 7 -- identical idiom to the proven 128^2 kernel, 0 confl.)
//
// Stage schedule per tile t (buf b = t&1), hazard-checked:
//   ph1 (mh0,ks0): stage A[t+1]H1 (buf b^1, dead since t-1 ph4) + B[t+1]H0 (b^1, dead)
//   ph2 (mh0,ks1): stage B[t+1]H1
//   ph3 (mh1,ks0): stage A[t+2]H0 into buf b region mh0 (last read ph2, barrier between)
//   ph4 (mh1,ks1): no stage; s_waitcnt vmcnt(2) (keeps A[t+2]H0 in flight) before barrier
// Prologue: A0H0,A0H1,B0H0,B0H1,A1H0 -> vmcnt(2) -> barrier.  Tail: drain to 0.
// Per-wave ledger: enter tile with 2 outstanding; +8 issued; vmcnt(2) leaves A[t+2]H0.
// =======================================================================================

#define BAR()   __builtin_amdgcn_s_barrier()
#define LGKM0() asm volatile("s_waitcnt lgkmcnt(0)" ::: "memory")
#define VMW2()  asm volatile("s_waitcnt vmcnt(2)" ::: "memory")
#define VMW0()  asm volatile("s_waitcnt vmcnt(0)" ::: "memory")
#define SCB0()  __builtin_amdgcn_sched_barrier(0)
#define PRIO(x) __builtin_amdgcn_s_setprio(x)

template<int EPI, int RESF32, int OUTF32>
__global__ __launch_bounds__(512, 2)
void gemm_bt(const bf16* __restrict__ A, const bf16* __restrict__ W,
             const float* __restrict__ bias, const float* __restrict__ bias2,
             const float* __restrict__ bias3, const void* __restrict__ res,
             void* __restrict__ C, int M, int N, int K, float scale)
{
    __shared__ __align__(16) char lds[131072];   // 128 KiB: 2 x (A 32K + B 32K)

    // T1: XCD-aware block swizzle (all grids have nwg % 8 == 0)
    const int nwgx = gridDim.x;
    const int nwg  = nwgx * gridDim.y;
    int bid = blockIdx.y * nwgx + blockIdx.x;
    bid = (bid & 7) * (nwg >> 3) + (bid >> 3);
    const int tile_n = (bid % nwgx) * 256;
    const int tile_m = (bid / nwgx) * 256;

    const int t = threadIdx.x;
    const int wave = t >> 6, lane = t & 63, quad = lane >> 4, l16 = lane & 15;
    const int wmp = wave >> 2, wnp = wave & 3;          // 2 M-waves x 4 N-waves
    const int Klen = K / gridDim.z, kbeg = blockIdx.z * Klen;
    const int NT = Klen >> 6;

    // ---- staging constants: each wave stages LDS rows wave*16 .. wave*16+15 ----------
    const int g8  = lane & 7;
    const int lr0 = wave * 16 + (lane >> 3);
    const int lr1 = lr0 + 8;
    const int c0 = (g8 - lr0) & 7, c1 = (g8 - lr1) & 7; // global k-chunk for this granule
    const size_t aof0 = (size_t)(tile_m + (lr0 >> 6) * 128 + (lr0 & 63)) * K + kbeg + c0 * 8;
    const size_t aof1 = (size_t)(tile_m + (lr1 >> 6) * 128 + (lr1 & 63)) * K + kbeg + c1 * 8;
    const size_t bof0 = (size_t)(tile_n + lr0) * K + kbeg + c0 * 8;
    const size_t bof1 = (size_t)(tile_n + lr1) * K + kbeg + c1 * 8;
    const int ls0 = wave * 2048, ls1 = wave * 2048 + 1024;   // wave-uniform LDS bases

    // ---- read constants ---------------------------------------------------------------
    const int ard = (wmp * 64 + l16) * 128;             // A row base within region
    const int brd = 32768 + (wnp * 64 + l16) * 128;     // B row base within buf
    const int gq0 = ((quad + l16) & 7) * 16;            // ks0 granule byte; ks1 = gq0^64

    floatx4 acc[8][4] = {};
    short8 av[4], bv0[4], bv1[4];

#define STAGE_A(_b, _mh, _kt) do { \
    glds16(lds + (_b) * 65536 + (_mh) * 16384 + ls0, \
           A + aof0 + (size_t)((_mh) * 64) * K + (_kt) * 64); \
    glds16(lds + (_b) * 65536 + (_mh) * 16384 + ls1, \
           A + aof1 + (size_t)((_mh) * 64) * K + (_kt) * 64); \
} while (0)

#define STAGE_B(_b, _h, _kt) do { \
    glds16(lds + (_b) * 65536 + 32768 + (_h) * 16384 + ls0, \
           W + bof0 + (size_t)((_h) * 128) * K + (_kt) * 64); \
    glds16(lds + (_b) * 65536 + 32768 + (_h) * 16384 + ls1, \
           W + bof1 + (size_t)((_h) * 128) * K + (_kt) * 64); \
} while (0)

#define LDA4(_b, _mh, _ks) do { \
    const char* _p = lds + (_b) * 65536 + (_mh) * 16384 + ard + (gq0 ^ ((_ks) * 64)); \
    av[0] = *(const short8*)(_p);        av[1] = *(const short8*)(_p + 2048); \
    av[2] = *(const short8*)(_p + 4096); av[3] = *(const short8*)(_p + 6144); \
} while (0)

#define LDB4(_b, _ks, _arr) do { \
    const char* _p = lds + (_b) * 65536 + brd + (gq0 ^ ((_ks) * 64)); \
    _arr[0] = *(const short8*)(_p);        _arr[1] = *(const short8*)(_p + 2048); \
    _arr[2] = *(const short8*)(_p + 4096); _arr[3] = *(const short8*)(_p + 6144); \
} while (0)

#define MFB(_mh, _bv) do { \
    _Pragma("unroll") \
    for (int _mi = 0; _mi < 4; ++_mi) { \
        _Pragma("unroll") \
        for (int _ni = 0; _ni < 4; ++_ni) \
            acc[(_mh) * 4 + _mi][_ni] = __builtin_amdgcn_mfma_f32_16x16x32_bf16( \
                av[_mi], _bv[_ni], acc[(_mh) * 4 + _mi][_ni], 0, 0, 0); \
    } \
} while (0)

#define TILE(_bb, _tt) do { \
    /* ph1: (mh0,ks0) */ \
    LDA4(_bb, 0, 0); LDB4(_bb, 0, bv0); \
    if ((_tt) + 1 < NT) { STAGE_A((_bb) ^ 1, 1, (_tt) + 1); STAGE_B((_bb) ^ 1, 0, (_tt) + 1); } \
    BAR(); LGKM0(); SCB0(); PRIO(1); MFB(0, bv0); PRIO(0); BAR(); \
    /* ph2: (mh0,ks1) */ \
    LDA4(_bb, 0, 1); LDB4(_bb, 1, bv1); \
    if ((_tt) + 1 < NT) STAGE_B((_bb) ^ 1, 1, (_tt) + 1); \
    BAR(); LGKM0(); SCB0(); PRIO(1); MFB(0, bv1); PRIO(0); BAR(); \
    /* ph3: (mh1,ks0) -- A[mh0] of this buf dead since ph2's trailing barrier */ \
    LDA4(_bb, 1, 0); \
    if ((_tt) + 2 < NT) STAGE_A(_bb, 0, (_tt) + 2); \
    BAR(); LGKM0(); SCB0(); PRIO(1); MFB(1, bv0); PRIO(0); BAR(); \
    /* ph4: (mh1,ks1) -- K-tile boundary: counted vmcnt BEFORE the barrier */ \
    LDA4(_bb, 1, 1); \
    BAR(); LGKM0(); SCB0(); PRIO(1); MFB(1, bv1); PRIO(0); \
    if ((_tt) + 2 < NT)      { VMW2(); } \
    else if ((_tt) + 1 < NT) { VMW0(); } \
    BAR(); \
} while (0)

    // ---- prologue: tile0 complete + A1 H0; keep A1H0 in flight ------------------------
    STAGE_A(0, 0, 0); STAGE_A(0, 1, 0);
    STAGE_B(0, 0, 0); STAGE_B(0, 1, 0);
    STAGE_A(1, 0, 1);
    VMW2();
    BAR();

    for (int tt = 0; tt < NT; tt += 2) {
        TILE(0, tt);
        TILE(1, tt + 1);
    }

#undef TILE
#undef MFB
#undef LDB4
#undef LDA4
#undef STAGE_B
#undef STAGE_A

    // ---- epilogue ---------------------------------------------------------------------
#pragma unroll
    for (int mi = 0; mi < 8; ++mi) {
        const int row0 = tile_m + wmp * 128 + mi * 16 + quad * 4;
#pragma unroll
        for (int ni = 0; ni < 4; ++ni) {
            const int col = tile_n + wnp * 64 + ni * 16 + l16;
            float bv = 0.f, sc = 1.f;
            if (EPI == 4) {
                if (col < 2048)      { bv = bias[col];         sc = scale; }
                else if (col < 4096) { bv = bias2[col - 2048]; }
                else                 { bv = bias3[col - 4096]; }
            } else if (EPI != 5) {
                bv = bias[col];
            }
#pragma unroll
            for (int r = 0; r < 4; ++r) {
                const size_t idx = (size_t)(row0 + r) * N + col;
                float v = acc[mi][ni][r];
                if (EPI == 5) { atomicAdd(&((float*)C)[idx], v); continue; }
                v += bv;
                if (EPI == 1) v *= scale;
                if (EPI == 4) v *= sc;
                if (EPI == 2) v = 0.5f * v * (1.0f + erff(v * 0.70710678118f));
                if (EPI == 3) v += RESF32 ? ((const float*)res)[idx] : bf2f(((const bf16*)res)[idx]);
                if (OUTF32) ((float*)C)[idx] = v;
                else        ((bf16*)C)[idx] = f2bf(v);
            }
        }
    }
}

// ---- Flash attention v2 (unchanged) ---------------------------------------------------
__global__ __launch_bounds__(256)
void flash_attn(const bf16* __restrict__ QKV, const float* __restrict__ mask,
                bf16* __restrict__ O)
{
    __shared__ __align__(16) bf16 Ks[4 * 64 * 32];
    __shared__ __align__(16) bf16 Vt[128 * 72];
    __shared__ __align__(16) bf16 Ps[4][16 * 72];
    const int bh = blockIdx.y, b = bh >> 4, h = bh & 15;
    const int t = threadIdx.x, w = t >> 6, lane = t & 63, quad = lane >> 4, l16 = lane & 15;
    const int qbase = blockIdx.x * 64 + w * 16;
    const size_t rowb = (size_t)b * Sc;
    const bf16* Kp = QKV + 2048 + (size_t)h * HDc;
    const bf16* Vp = QKV + 4096 + (size_t)h * HDc;

    short8 qf[4];
    {
        const bf16* qp = QKV + (rowb + qbase + l16) * QKVLD + (size_t)h * HDc + quad * 8;
#pragma unroll
        for (int kc = 0; kc < 4; ++kc) qf[kc] = *(const short8*)(qp + kc * 32);
    }
    float m_i[4], l_i[4];
    floatx4 Oacc[8] = {};
#pragma unroll
    for (int r = 0; r < 4; ++r) { m_i[r] = -1e30f; l_i[r] = 0.f; }

    const int p2 = t & 31, dg = t >> 5;

    for (int kt = 0; kt < Sc; kt += 64) {
        __syncthreads();
#pragma unroll
        for (int u = 0; u < 4; ++u) {
            const int row = u * 16 + (lane >> 2);
            glds16((char*)Ks + w * 4096 + u * 1024,
                   Kp + (rowb + kt + row) * QKVLD + w * 32 + (lane & 3) * 8);
        }
        {
            union { uint4 u4; unsigned short s[8]; } va[2][2];
#pragma unroll
            for (int kk = 0; kk < 2; ++kk) {
                const bf16* vp = Vp + (rowb + kt + 2 * p2 + kk) * QKVLD + dg * 16;
                va[kk][0].u4 = *(const uint4*)vp;
                va[kk][1].u4 = *(const uint4*)(vp + 8);
            }
            unsigned* VtW = (unsigned*)Vt;
#pragma unroll
            for (int j = 0; j < 16; ++j) {
                const unsigned word = (unsigned)va[0][j >> 3].s[j & 7]
                                    | ((unsigned)va[1][j >> 3].s[j & 7] << 16);
                VtW[(dg * 16 + j) * 36 + p2] = word;
            }
        }
        __syncthreads();

        floatx4 sacc[4] = {};
#pragma unroll
        for (int kc = 0; kc < 4; ++kc)
#pragma unroll
            for (int sub = 0; sub < 4; ++sub) {
                short8 kf = *(const short8*)&Ks[kc * 2048 + (sub * 16 + l16) * 32 + quad * 8];
                sacc[sub] = __builtin_amdgcn_mfma_f32_16x16x32_bf16(qf[kc], kf, sacc[sub], 0, 0, 0);
            }
#pragma unroll
        for (int sub = 0; sub < 4; ++sub) {
            const float mv = mask[b * Sc + kt + sub * 16 + l16];
            const float madd = (mv < 0.5f) ? -3.0e38f : 0.f;
#pragma unroll
            for (int r = 0; r < 4; ++r) sacc[sub][r] += madd;
        }
        float p[4][4], alpha[4];
#pragma unroll
        for (int r = 0; r < 4; ++r) {
            float mx = fmaxf(fmaxf(sacc[0][r], sacc[1][r]), fmaxf(sacc[2][r], sacc[3][r]));
#pragma unroll
            for (int off = 8; off; off >>= 1) mx = fmaxf(mx, __shfl_xor(mx, off));
            const float mnew = fmaxf(m_i[r], mx);
            alpha[r] = exp2f(m_i[r] - mnew);
            float ps = 0.f;
#pragma unroll
            for (int sub = 0; sub < 4; ++sub) { p[sub][r] = exp2f(sacc[sub][r] - mnew); ps += p[sub][r]; }
#pragma unroll
            for (int off = 8; off; off >>= 1) ps += __shfl_xor(ps, off);
            l_i[r] = l_i[r] * alpha[r] + ps;
            m_i[r] = mnew;
        }
#pragma unroll
        for (int nsub = 0; nsub < 8; ++nsub)
#pragma unroll
            for (int r = 0; r < 4; ++r) Oacc[nsub][r] *= alpha[r];

        bf16* Pw = Ps[w];
#pragma unroll
        for (int sub = 0; sub < 4; ++sub)
#pragma unroll
            for (int r = 0; r < 4; ++r)
                Pw[(quad * 4 + r) * 72 + sub * 16 + l16] = f2bf(p[sub][r]);
        const short8 pf0 = *(const short8*)&Pw[l16 * 72 + quad * 8];
        const short8 pf1 = *(const short8*)&Pw[l16 * 72 + 32 + quad * 8];
#pragma unroll
        for (int nsub = 0; nsub < 8; ++nsub) {
            const short8 vf0 = *(const short8*)&Vt[(nsub * 16 + l16) * 72 + quad * 8];
            const short8 vf1 = *(const short8*)&Vt[(nsub * 16 + l16) * 72 + 32 + quad * 8];
            Oacc[nsub] = __builtin_amdgcn_mfma_f32_16x16x32_bf16(pf0, vf0, Oacc[nsub], 0, 0, 0);
            Oacc[nsub] = __builtin_amdgcn_mfma_f32_16x16x32_bf16(pf1, vf1, Oacc[nsub], 0, 0, 0);
        }
    }

#pragma unroll
    for (int r = 0; r < 4; ++r) {
        const float inv = 1.f / l_i[r];
        bf16* orow = O + (rowb + qbase + quad * 4 + r) * Dc + (size_t)h * HDc;
#pragma unroll
        for (int nsub = 0; nsub < 8; ++nsub)
            orow[nsub * 16 + l16] = f2bf(Oacc[nsub][r] * inv);
    }
}

// ---------------------------------- launcher ------------------------------------------
extern "C" void kernel_launch(void* const* d_in, const int* in_sizes, int n_in,
                              void* d_out, int out_size, void* d_ws, size_t ws_size,
                              hipStream_t stream)
{
    const float* hidden = (const float*)d_in[1];
    const float* amask  = (const float*)d_in[2];
    const float* Wq = (const float*)d_in[4];  const float* bq = (const float*)d_in[5];
    const float* Wk = (const float*)d_in[6];  const float* bk = (const float*)d_in[7];
    const float* Wv = (const float*)d_in[8];  const float* bv = (const float*)d_in[9];
    const float* Wo = (const float*)d_in[10]; const float* bo = (const float*)d_in[11];
    const float* ln1w = (const float*)d_in[12]; const float* ln1b = (const float*)d_in[13];
    const float* ln2w = (const float*)d_in[14]; const float* ln2b = (const float*)d_in[15];
    const float* W1 = (const float*)d_in[16]; const float* b1 = (const float*)d_in[17];
    const float* W2 = (const float*)d_in[18]; const float* b2 = (const float*)d_in[19];

    const size_t UE = 8ull * 1024 * 1024;     // elements per 16 MB bf16 unit
    const size_t WE = 4ull * 1024 * 1024;     // elements per D*D weight
    bf16*  U = (bf16*)d_ws;
    bf16*  qkv   = U;                         // U0-U2 (48 MB) [4096][6144]
    bf16*  wbuf  = U + 4 * UE;                // U4-U5 (32 MB): Wq|Wk|Wv|Wo, then W1, then W2
    bf16*  x_ln  = U + 6 * UE;                // U6 (dead after QKV gemm)
    float* hid2f = (float*)(U + 6 * UE);      // U6-U7 fp32 32 MB (overlays x_ln)
    bf16*  ffn1  = U;                         // U0-U3 (64 MB; qkv dead)
    bf16*  attn  = (bf16*)d_out;              // d_out[0:16MB)
    bf16*  y_ln  = (bf16*)d_out + UE;         // d_out[16:32MB)
    float* outf  = (float*)d_out;

    const float qscale = 0.08838834764831845f * 1.4426950408889634f; // HD^-0.5 * log2e
    const dim3 gQKV(QKVLD / 256, Bc * Sc / 256, 1);  // (24,16)
    const dim3 gWo (Dc / 256,    Bc * Sc / 256, 2);  // (8,16,2) split-K
    const dim3 gF1 (Ic / 256,    Bc * Sc / 256, 1);  // (32,16)
    const dim3 gF2 (Dc / 256,    Bc * Sc / 256, 2);  // (8,16,2) split-K

    conv_w4<<<8192, 256, 0, stream>>>(Wq, Wk, Wv, Wo, wbuf);
    ln_kernel<1><<<Bc * Sc, 256, 0, stream>>>(hidden, ln1w, ln1b, x_ln);
    gemm_bt<4,0,0><<<gQKV, 512, 0, stream>>>(x_ln, wbuf, bq, bk, bv, nullptr, qkv,
                                             Bc * Sc, QKVLD, Dc, qscale);
    flash_attn<<<dim3(Sc / 64, Bc * Hc), 256, 0, stream>>>(qkv, amask, attn);
    init_add<<<4096, 256, 0, stream>>>(hid2f, bo, hidden);              // hid2f = bo + hidden
    gemm_bt<5,0,1><<<gWo, 512, 0, stream>>>(attn, wbuf + 3 * WE, nullptr, nullptr, nullptr,
                                            nullptr, hid2f, Bc * Sc, Dc, Dc, 0.f);
    ln_kernel<1><<<Bc * Sc, 256, 0, stream>>>(hid2f, ln2w, ln2b, y_ln);
    conv_w<<<8192, 256, 0, stream>>>(W1, wbuf);
    gemm_bt<2,0,0><<<gF1, 512, 0, stream>>>(y_ln, wbuf, b1, nullptr, nullptr, nullptr, ffn1,
                                            Bc * Sc, Ic, Dc, 0.f);
    init_add<<<4096, 256, 0, stream>>>(outf, b2, hid2f);                // d_out = b2 + hid2f
    conv_w<<<8192, 256, 0, stream>>>(W2, wbuf);
    gemm_bt<5,0,1><<<gF2, 512, 0, stream>>>(ffn1, wbuf, nullptr, nullptr, nullptr,
                                            nullptr, outf, Bc * Sc, Dc, Ic, 0.f);
}